// Round 3
// baseline (175.232 us; speedup 1.0000x reference)
//
#include <hip/hip_runtime.h>

#define HH 160
#define WW 160
#define DD 160
#define BB 4

typedef float vfloat4 __attribute__((ext_vector_type(4)));

// ---- monotone float<->uint mapping for atomic min on floats ----
__device__ __forceinline__ unsigned mapf(float f) {
    unsigned b = __float_as_uint(f);
    return (b & 0x80000000u) ? ~b : (b | 0x80000000u);
}
__device__ __forceinline__ float unmapf(unsigned k) {
    unsigned b = (k & 0x80000000u) ? (k ^ 0x80000000u) : ~k;
    return __uint_as_float(b);
}

// ---- kernel 1: per-batch min reduction (fill value) + affine constants ----
// grid (1024, BB) x 256. Each thread: 4 independent strided float4 loads
// (MLP=4 to hide HBM latency). Block (0,0) additionally computes the fp64
// affine constants:
//   ix = R00*x + R01*y + R02*z + 79.5*(t0 - R00 - R01 - R02 + 1)
// (exact fold of linspace + cx scaling, since 79.5*(2/159) == 1).
__global__ __launch_bounds__(256) void min_cst_kernel(const float4* __restrict__ img4,
                                                      const float* __restrict__ transfos,
                                                      unsigned* __restrict__ minkey,
                                                      double* __restrict__ cst) {
    const int b = blockIdx.y;
    const int NB = HH * WW * DD / 4;               // 1,024,000 float4 per batch
    const size_t base = (size_t)b * NB;
    const int idx = blockIdx.x * 256 + threadIdx.x;  // < 262144
    const int S = 262144;

    float4 v0 = img4[base + idx];
    float4 v1 = img4[base + idx + S];
    float4 v2 = img4[base + idx + 2 * S];
    float4 v3 = make_float4(3.4e38f, 3.4e38f, 3.4e38f, 3.4e38f);
    if (idx + 3 * S < NB) v3 = img4[base + idx + 3 * S];

    float m = fminf(fminf(fminf(v0.x, v0.y), fminf(v0.z, v0.w)),
                    fminf(fminf(v1.x, v1.y), fminf(v1.z, v1.w)));
    m = fminf(m, fminf(fminf(v2.x, v2.y), fminf(v2.z, v2.w)));
    m = fminf(m, fminf(fminf(v3.x, v3.y), fminf(v3.z, v3.w)));

    #pragma unroll
    for (int o = 32; o >= 1; o >>= 1) m = fminf(m, __shfl_down(m, o));
    __shared__ float s[4];
    const int lane = threadIdx.x & 63, wid = threadIdx.x >> 6;
    if (lane == 0) s[wid] = m;
    __syncthreads();
    if (threadIdx.x == 0) {
        m = fminf(fminf(s[0], s[1]), fminf(s[2], s[3]));
        atomicMin(&minkey[b], mapf(m));
    }

    // affine constants (fp64), once per batch, by block (0,0) threads 0..3
    if (blockIdx.x == 0 && blockIdx.y == 0 && threadIdx.x < BB) {
        const int bb = threadIdx.x;
        const float* q = transfos + bb * 7;
        double x = q[0], y = q[1], z = q[2], w = q[3];
        double tx = 2.0 * x, ty = 2.0 * y, tz = 2.0 * z;
        double twx = tx * w, twy = ty * w, twz = tz * w;
        double txx = tx * x, txy = ty * x, txz = tz * x;
        double tyy = ty * y, tyz = tz * y, tzz = tz * z;
        double R[3][3] = {
            {1.0 - (tyy + tzz), txy - twz,         txz + twy},
            {txy + twz,         1.0 - (txx + tzz), tyz - twx},
            {txz - twy,         tyz + twx,         1.0 - (txx + tyy)}
        };
        double t[3] = {(double)q[4], (double)q[5], (double)q[6]};
        for (int r = 0; r < 3; r++) {
            cst[bb * 12 + r * 4 + 0] = R[r][0];
            cst[bb * 12 + r * 4 + 1] = R[r][1];
            cst[bb * 12 + r * 4 + 2] = R[r][2];
            cst[bb * 12 + r * 4 + 3] = 79.5 * (t[r] - R[r][0] - R[r][1] - R[r][2] + 1.0);
        }
    }
}

// ---- kernel 2: affine map + trilinear gather, 4 z-outputs per thread ----
// grid (25, 160, 4) x 256. thread t in [0,6400): x = t/40, z base = (t%40)*4.
__global__ __launch_bounds__(256) void st3d_kernel(const float* __restrict__ img,
                                                   const double* __restrict__ cst,
                                                   const unsigned* __restrict__ minkey,
                                                   float* __restrict__ out) {
    const int b = blockIdx.z;
    const int y = blockIdx.y;
    const int t = blockIdx.x * 256 + threadIdx.x;   // [0, 6400)
    const int x = t / 40;
    const int zq = (t - 40 * x) * 4;

    const double* c = cst + b * 12;
    const double c2 = c[2], c6 = c[6], c10 = c[10];
    const double dx = (double)x, dy = (double)y, dz = (double)zq;
    double ixd = fma(c[0], dx, fma(c[1], dy, fma(c2, dz, c[3])));
    double iyd = fma(c[4], dx, fma(c[5], dy, fma(c6, dz, c[7])));
    double izd = fma(c[8], dx, fma(c[9], dy, fma(c10, dz, c[11])));

    const float fill = unmapf(minkey[b]);
    const float* base = img + (size_t)b * (HH * WW * DD);

    vfloat4 r;
    #pragma unroll
    for (int k = 0; k < 4; k++) {
        float res = fill;
        const bool valid = (ixd >= 0.0) && (ixd <= 159.0) && (iyd >= 0.0) &&
                           (iyd <= 159.0) && (izd >= 0.0) && (izd <= 159.0);
        if (valid) {
            double flx = floor(ixd), fly = floor(iyd), flz = floor(izd);
            int x0 = (int)flx, y0 = (int)fly, z0 = (int)flz;
            float fx = (float)(ixd - flx), fy = (float)(iyd - fly), fz = (float)(izd - flz);
            int x1 = min(x0 + 1, 159), y1 = min(y0 + 1, 159), z1 = min(z0 + 1, 159);
            // img[b, h=yi, w=xi, d=zi]
            const float* p00 = base + ((size_t)y0 * WW + x0) * DD;  // (y0, x0)
            const float* p01 = base + ((size_t)y0 * WW + x1) * DD;  // (y0, x1)
            const float* p10 = base + ((size_t)y1 * WW + x0) * DD;  // (y1, x0)
            const float* p11 = base + ((size_t)y1 * WW + x1) * DD;  // (y1, x1)
            float v000 = p00[z0], v001 = p00[z1];
            float v010 = p10[z0], v011 = p10[z1];
            float v100 = p01[z0], v101 = p01[z1];
            float v110 = p11[z0], v111 = p11[z1];
            float wx0 = 1.0f - fx, wx1 = fx;
            float wy0 = 1.0f - fy, wy1 = fy;
            float wz0 = 1.0f - fz, wz1 = fz;
            // accumulate in the reference's (ox, oy, oz) loop order
            float acc;
            acc  = ((wx0 * wy0) * wz0) * v000;
            acc += ((wx0 * wy0) * wz1) * v001;
            acc += ((wx0 * wy1) * wz0) * v010;
            acc += ((wx0 * wy1) * wz1) * v011;
            acc += ((wx1 * wy0) * wz0) * v100;
            acc += ((wx1 * wy0) * wz1) * v101;
            acc += ((wx1 * wy1) * wz0) * v110;
            acc += ((wx1 * wy1) * wz1) * v111;
            res = acc;
        }
        r[k] = res;
        ixd += c2; iyd += c6; izd += c10;
    }

    vfloat4* outp = (vfloat4*)(out + (size_t)(b * HH + y) * (WW * DD) + x * DD + zq);
    __builtin_nontemporal_store(r, outp);
}

extern "C" void kernel_launch(void* const* d_in, const int* in_sizes, int n_in,
                              void* d_out, int out_size, void* d_ws, size_t ws_size,
                              hipStream_t stream) {
    const float* img = (const float*)d_in[0];
    const float* transfos = (const float*)d_in[1];
    float* out = (float*)d_out;
    unsigned* minkey = (unsigned*)d_ws;
    double* cst = (double*)((char*)d_ws + 64);

    (void)hipMemsetAsync(minkey, 0xFF, BB * sizeof(unsigned), stream);
    min_cst_kernel<<<dim3(1024, BB), 256, 0, stream>>>((const float4*)img, transfos, minkey, cst);
    st3d_kernel<<<dim3(25, 160, BB), 256, 0, stream>>>(img, cst, minkey, out);
}

// Round 4
// 131.931 us; speedup vs baseline: 1.3282x; 1.3282x over previous
//
#include <hip/hip_runtime.h>

#define HH 160
#define WW 160
#define DD 160
#define BB 4
#define NPB (HH * WW * DD / 4)   // 1,024,000 float4 per batch
#define K1B 256                   // min-pass blocks per batch

typedef float vfloat4 __attribute__((ext_vector_type(4)));

// ---- kernel 1: per-batch block-partial min (NO atomics) + affine constants ----
// grid (256, BB) x 256. Each thread reads 16 float4 (4 rounds, MLP=4),
// stride 65536 float4. Block partial min -> partial[b*256 + bx].
// Block (0, y=0) threads 0..3 also compute fp64 affine constants:
//   ix = R00*x + R01*y + R02*z + 79.5*(t0 - R00 - R01 - R02 + 1)
// (exact fold of linspace + cx scaling, since 79.5*(2/159) == 1).
__global__ __launch_bounds__(256) void min_cst_kernel(const float4* __restrict__ img4,
                                                      const float* __restrict__ transfos,
                                                      float* __restrict__ partial,
                                                      double* __restrict__ cst) {
    const int b = blockIdx.y;
    const size_t base = (size_t)b * NPB;
    const int t0 = blockIdx.x * 256 + threadIdx.x;   // < 65536
    const int S = K1B * 256;                          // 65536

    float m = 3.4e38f;
    #pragma unroll
    for (int r = 0; r < 4; r++) {
        const int i0 = t0 + 4 * r * S;
        float4 v0 = img4[base + i0];
        float4 v1 = img4[base + i0 + S];
        float4 v2 = img4[base + i0 + 2 * S];
        float4 v3 = make_float4(3.4e38f, 3.4e38f, 3.4e38f, 3.4e38f);
        if (i0 + 3 * S < NPB) v3 = img4[base + i0 + 3 * S];   // only r==3 can fail
        m = fminf(m, fminf(fminf(v0.x, v0.y), fminf(v0.z, v0.w)));
        m = fminf(m, fminf(fminf(v1.x, v1.y), fminf(v1.z, v1.w)));
        m = fminf(m, fminf(fminf(v2.x, v2.y), fminf(v2.z, v2.w)));
        m = fminf(m, fminf(fminf(v3.x, v3.y), fminf(v3.z, v3.w)));
    }

    #pragma unroll
    for (int o = 32; o >= 1; o >>= 1) m = fminf(m, __shfl_down(m, o));
    __shared__ float s[4];
    const int lane = threadIdx.x & 63, wid = threadIdx.x >> 6;
    if (lane == 0) s[wid] = m;
    __syncthreads();
    if (threadIdx.x == 0) {
        partial[b * K1B + blockIdx.x] =
            fminf(fminf(s[0], s[1]), fminf(s[2], s[3]));
    }

    // affine constants (fp64), once per batch, by block (0,0) threads 0..3
    if (blockIdx.x == 0 && blockIdx.y == 0 && threadIdx.x < BB) {
        const int bb = threadIdx.x;
        const float* q = transfos + bb * 7;
        double x = q[0], y = q[1], z = q[2], w = q[3];
        double tx = 2.0 * x, ty = 2.0 * y, tz = 2.0 * z;
        double twx = tx * w, twy = ty * w, twz = tz * w;
        double txx = tx * x, txy = ty * x, txz = tz * x;
        double tyy = ty * y, tyz = tz * y, tzz = tz * z;
        double R[3][3] = {
            {1.0 - (tyy + tzz), txy - twz,         txz + twy},
            {txy + twz,         1.0 - (txx + tzz), tyz - twx},
            {txz - twy,         tyz + twx,         1.0 - (txx + tyy)}
        };
        double t[3] = {(double)q[4], (double)q[5], (double)q[6]};
        for (int r = 0; r < 3; r++) {
            cst[bb * 12 + r * 4 + 0] = R[r][0];
            cst[bb * 12 + r * 4 + 1] = R[r][1];
            cst[bb * 12 + r * 4 + 2] = R[r][2];
            cst[bb * 12 + r * 4 + 3] = 79.5 * (t[r] - R[r][0] - R[r][1] - R[r][2] + 1.0);
        }
    }
}

// ---- kernel 2: affine map + trilinear gather, 4 z-outputs per thread ----
// grid (25, 160, 4) x 256. thread t in [0,6400): x = t/40, z base = (t%40)*4.
// Block start: reduce the 256 partial mins of this batch -> fill.
__global__ __launch_bounds__(256) void st3d_kernel(const float* __restrict__ img,
                                                   const double* __restrict__ cst,
                                                   const float* __restrict__ partial,
                                                   float* __restrict__ out) {
    const int b = blockIdx.z;
    const int y = blockIdx.y;

    // ---- fill = min over this batch's 256 partials ----
    __shared__ float sred[4];
    float pm = partial[b * K1B + threadIdx.x];
    #pragma unroll
    for (int o = 32; o >= 1; o >>= 1) pm = fminf(pm, __shfl_down(pm, o));
    if ((threadIdx.x & 63) == 0) sred[threadIdx.x >> 6] = pm;
    __syncthreads();
    const float fill = fminf(fminf(sred[0], sred[1]), fminf(sred[2], sred[3]));

    const int t = blockIdx.x * 256 + threadIdx.x;   // [0, 6400)
    const int x = t / 40;
    const int zq = (t - 40 * x) * 4;

    const double* c = cst + b * 12;
    const double c2 = c[2], c6 = c[6], c10 = c[10];
    const double dx = (double)x, dy = (double)y, dz = (double)zq;
    double ixd = fma(c[0], dx, fma(c[1], dy, fma(c2, dz, c[3])));
    double iyd = fma(c[4], dx, fma(c[5], dy, fma(c6, dz, c[7])));
    double izd = fma(c[8], dx, fma(c[9], dy, fma(c10, dz, c[11])));

    const float* base = img + (size_t)b * (HH * WW * DD);

    vfloat4 r;
    #pragma unroll
    for (int k = 0; k < 4; k++) {
        float res = fill;
        const bool valid = (ixd >= 0.0) && (ixd <= 159.0) && (iyd >= 0.0) &&
                           (iyd <= 159.0) && (izd >= 0.0) && (izd <= 159.0);
        if (valid) {
            double flx = floor(ixd), fly = floor(iyd), flz = floor(izd);
            int x0 = (int)flx, y0 = (int)fly, z0 = (int)flz;
            float fx = (float)(ixd - flx), fy = (float)(iyd - fly), fz = (float)(izd - flz);
            int x1 = min(x0 + 1, 159), y1 = min(y0 + 1, 159), z1 = min(z0 + 1, 159);
            // img[b, h=yi, w=xi, d=zi]
            const float* p00 = base + ((size_t)y0 * WW + x0) * DD;  // (y0, x0)
            const float* p01 = base + ((size_t)y0 * WW + x1) * DD;  // (y0, x1)
            const float* p10 = base + ((size_t)y1 * WW + x0) * DD;  // (y1, x0)
            const float* p11 = base + ((size_t)y1 * WW + x1) * DD;  // (y1, x1)
            float v000 = p00[z0], v001 = p00[z1];
            float v010 = p10[z0], v011 = p10[z1];
            float v100 = p01[z0], v101 = p01[z1];
            float v110 = p11[z0], v111 = p11[z1];
            float wx0 = 1.0f - fx, wx1 = fx;
            float wy0 = 1.0f - fy, wy1 = fy;
            float wz0 = 1.0f - fz, wz1 = fz;
            // accumulate in the reference's (ox, oy, oz) loop order
            float acc;
            acc  = ((wx0 * wy0) * wz0) * v000;
            acc += ((wx0 * wy0) * wz1) * v001;
            acc += ((wx0 * wy1) * wz0) * v010;
            acc += ((wx0 * wy1) * wz1) * v011;
            acc += ((wx1 * wy0) * wz0) * v100;
            acc += ((wx1 * wy0) * wz1) * v101;
            acc += ((wx1 * wy1) * wz0) * v110;
            acc += ((wx1 * wy1) * wz1) * v111;
            res = acc;
        }
        r[k] = res;
        ixd += c2; iyd += c6; izd += c10;
    }

    vfloat4* outp = (vfloat4*)(out + (size_t)(b * HH + y) * (WW * DD) + x * DD + zq);
    __builtin_nontemporal_store(r, outp);
}

extern "C" void kernel_launch(void* const* d_in, const int* in_sizes, int n_in,
                              void* d_out, int out_size, void* d_ws, size_t ws_size,
                              hipStream_t stream) {
    const float* img = (const float*)d_in[0];
    const float* transfos = (const float*)d_in[1];
    float* out = (float*)d_out;
    float* partial = (float*)d_ws;                      // 1024 floats
    double* cst = (double*)((char*)d_ws + 4096);        // 48 doubles

    min_cst_kernel<<<dim3(K1B, BB), 256, 0, stream>>>((const float4*)img, transfos,
                                                      partial, cst);
    st3d_kernel<<<dim3(25, 160, BB), 256, 0, stream>>>(img, cst, partial, out);
}